// Round 16
// baseline (96.429 us; speedup 1.0000x reference)
//
#include <hip/hip_runtime.h>
#include <math.h>

#define NB 8
#define NF 4000
#define NFRAMES (NB * NF)

// ---- filter taps (first half; symmetric). Double literals -> f32 at compile
// time, matching numpy float64 -> float32 conversion exactly.
__constant__ float c_hhp[21] = {
    0.00041447996898231424, 0.0007812505141729248, -0.0010917236836275842,
    -0.001986792567596759,  0.0020903896961562292, 0.004094057027284935,
    -0.0034025808529816698, -0.007496154127205602, 0.004972263339933064,
    0.012738791249119802,   -0.006696032689574911, -0.020694051570247052,
    0.008432436565041345,   0.03307438375870053,   -0.010018936738799522,
    -0.05423136140580825,   0.011293988915051487,  0.10020081367388213,
    -0.012120546202484579,  -0.316300210390957,    0.5124068258062764};
__constant__ float c_hlp[19] = {
    -0.0006548817007748305, 7.561994958159384e-05, 0.0020408456937895227,
    -0.0007468053532203044, -0.004350223568826493, 0.0025966428382642732,
    0.007639602282756696,   -0.006490411890149785, -0.011765804538954506,
    0.013649908479276255,   0.01636866479016021,   -0.026075976030529347,
    -0.020910294856659444,  0.04826072503231665,   0.02476784661104811,
    -0.09617846758336064,   -0.027359756709866623, 0.3148805216163004,
    0.5282734359405503};

__device__ __forceinline__ int reflidx(int i, int len) {
  if (i < 0) i = -i;
  if (i >= len) i = 2 * len - 2 - i;
  return i;
}
__device__ __forceinline__ int clampi(int i, int hi) {
  return min(max(i, 0), hi);
}
// dwordx4 load/store; AMD global VMEM requires only dword alignment.
__device__ __forceinline__ float4 ld4(const float* p) {
  return *reinterpret_cast<const float4*>(p);
}
__device__ __forceinline__ void st4(float* p, float4 v) {
  *reinterpret_cast<float4*>(p) = v;
}

// ---- QMF stage: stride-2 correlation with reflect padding, both filters.
// If wtab != null, one extra block initializes the window tables (padded with
// zeros to 256 entries per band -- the band kernel relies on those zeros).
__global__ __launch_bounds__(256) void qmf_kernel(
    const float* __restrict__ in, int len, float* __restrict__ outH,
    float* __restrict__ outL, float2* __restrict__ wtab) {
  int half = len >> 1;
  int gid = blockIdx.x * 256 + threadIdx.x;
  if (gid >= NB * half) {
    if (wtab) {
      const int segs[4] = {241, 121, 61, 61};
      int k = threadIdx.x;
      for (int i = 0; i < 4; ++i) {
        float v = 0.f;
        if (k < segs[i]) {
          double ang = 2.0 * 3.14159265358979323846 * (double)(k + 1) /
                       (double)(segs[i] + 1);
          v = (float)(0.5 - 0.5 * cos(ang));
        }
        wtab[i * 256 + k] = make_float2(v, sqrtf(v));
      }
    }
    return;
  }
  int b = gid / half;
  int nn = gid - b * half;
  const float* row = in + (size_t)b * len;
  int c = 2 * nn;
  float sh = 0.f, sl = 0.f;
  if (c >= 20 && c <= len - 22) {
    const float2* p2 = reinterpret_cast<const float2*>(row + (c - 20));
    float v[42];
#pragma unroll
    for (int j = 0; j < 21; ++j) {
      float2 t = p2[j];
      v[2 * j] = t.x;
      v[2 * j + 1] = t.y;
    }
#pragma unroll
    for (int t = 0; t < 41; ++t) sh += v[t] * c_hhp[t <= 20 ? t : 40 - t];
#pragma unroll
    for (int t = 0; t < 37; ++t) sl += v[t + 2] * c_hlp[t <= 18 ? t : 36 - t];
  } else {
#pragma unroll
    for (int t = 0; t < 41; ++t)
      sh += row[reflidx(c + t - 20, len)] * c_hhp[t <= 20 ? t : 40 - t];
#pragma unroll
    for (int t = 0; t < 37; ++t)
      sl += row[reflidx(c + t - 18, len)] * c_hlp[t <= 18 ? t : 36 - t];
  }
  outH[(size_t)b * half + nn] = sh;
  outL[(size_t)b * half + nn] = sl;
}

__device__ __forceinline__ void accum1(float wk, float wsk, float h0, float h1,
                                       float h2, float h3, float h4, float h5,
                                       float x, float* __restrict__ rr,
                                       float* __restrict__ bv,
                                       float* __restrict__ gv, float& sxx,
                                       float& s1x) {
  sxx += wk * x * x;
  s1x += wsk * x;
  float wh0 = wk * h0, wh1 = wk * h1, wh2 = wk * h2, wh3 = wk * h3,
        wh4 = wk * h4, wh5 = wk * h5;
  gv[0] += wsk * h0; gv[1] += wsk * h1; gv[2] += wsk * h2;
  gv[3] += wsk * h3; gv[4] += wsk * h4; gv[5] += wsk * h5;
  bv[0] += wh0 * x;  bv[1] += wh1 * x;  bv[2] += wh2 * x;
  bv[3] += wh3 * x;  bv[4] += wh4 * x;  bv[5] += wh5 * x;
  rr[0] += wh0 * h0;  rr[1] += wh0 * h1;  rr[2] += wh0 * h2;
  rr[3] += wh0 * h3;  rr[4] += wh0 * h4;  rr[5] += wh0 * h5;
  rr[6] += wh1 * h1;  rr[7] += wh1 * h2;  rr[8] += wh1 * h3;
  rr[9] += wh1 * h4;  rr[10] += wh1 * h5; rr[11] += wh2 * h2;
  rr[12] += wh2 * h3; rr[13] += wh2 * h4; rr[14] += wh2 * h5;
  rr[15] += wh3 * h3; rr[16] += wh3 * h4; rr[17] += wh3 * h5;
  rr[18] += wh4 * h4; rr[19] += wh4 * h5; rr[20] += wh5 * h5;
}

// ---- mega kernel: all 4 bands + solve + log-interp-exp, one block = 8 frames.
// 32 lanes per frame: lanes 0-15 band0 (GS=16), 16-23 band1 (GS=8),
// 24-27 band2 (GS=4), 28-31 band3 (GS=4). 4 samples/lane/iter, 4 iters for
// ALL lanes (KMAX = 256/128/64/64, zero-padded windows). Uniform blocks.
__global__ __launch_bounds__(256) void bands_interp_kernel(
    const float* __restrict__ hx0, const float* __restrict__ hx1,
    const float* __restrict__ hx2, const float* __restrict__ lx2,
    const float* __restrict__ f0, const float2* __restrict__ wtab,
    float* __restrict__ out) {
  __shared__ float lds_l[8][4];
  const int tid = threadIdx.x;
  const int fslot = tid >> 5;        // 0..7: frame slot in block
  const int lane32 = tid & 31;
  const int frame = blockIdx.x * 8 + fslot;
  const int b = frame / NF;
  const int n = frame - b * NF;

  // band mapping (uniform within each lane group)
  int band, base, gs;
  const float* xb;
  int bandLen;
  float tmp_fs;
  if (lane32 < 16) {
    band = 0; base = 0;  gs = 16; xb = hx0; bandLen = 160000; tmp_fs = 8000.f;
  } else if (lane32 < 24) {
    band = 1; base = 16; gs = 8;  xb = hx1; bandLen = 80000;  tmp_fs = 4000.f;
  } else if (lane32 < 28) {
    band = 2; base = 24; gs = 4;  xb = hx2; bandLen = 40000;  tmp_fs = 2000.f;
  } else {
    band = 3; base = 28; gs = 4;  xb = lx2; bandLen = 40000;  tmp_fs = 2000.f;
  }
  const int sub = lane32 - base;
  const float2* wt = wtab + band * 256;

  float f0v = f0[frame];
  if (f0v <= 32.0f) f0v = 150.0f;
  // replicate JAX f32 op sequence exactly (no FMA contraction):
  float pitch = tmp_fs / f0v;
  int t0 = (int)(__fadd_rn(pitch, 0.5f));
  int ibias = (int)(__fadd_rn(__fmul_rn(pitch, 0.5f), 0.5f));
  float tt = __fmul_rn((float)n, 0.005f);  // FRAME_PERIOD/SR as f32
  int curr = (int)(__fadd_rn(__fmul_rn(tt, tmp_fs), 1.5f));
  int origin = curr - ibias;
  const int T1 = bandLen - 1;
  const float* row = xb + (size_t)b * bandLen;
  const int base_a = origin - t0 - 1;
  const int base_b = origin + t0 - 1;
  const int kmax = gs << 4;  // 4 * gs * NITER(4)

  float rr[21], bv[6], gv[6], sxx = 0.f, s1x = 0.f;
#pragma unroll
  for (int i = 0; i < 21; ++i) rr[i] = 0.f;
#pragma unroll
  for (int i = 0; i < 6; ++i) bv[i] = 0.f;
#pragma unroll
  for (int i = 0; i < 6; ++i) gv[i] = 0.f;

  const bool fast = (base_a >= 0) && (base_b + kmax + 3 <= T1);
  if (fast) {
    const float* pa = row + base_a + 4 * sub;
    const float* pb = row + base_b + 4 * sub;
    const float* pg = row + origin + 4 * sub;
    const float* pw = reinterpret_cast<const float*>(wt + 4 * sub);
#pragma unroll
    for (int j = 0; j < 4; ++j) {
      const int off = j * 4 * gs;
      float4 a0 = ld4(pa + off);
      float4 a1 = ld4(pa + off + 4);
      float4 b0 = ld4(pb + off);
      float4 b1 = ld4(pb + off + 4);
      float4 xx = ld4(pg + off);
      float4 w01 = ld4(pw + 2 * off);
      float4 w23 = ld4(pw + 2 * off + 4);
      accum1(w01.x, w01.y, a0.x, a0.y, a0.z, b0.x, b0.y, b0.z, xx.x, rr, bv,
             gv, sxx, s1x);
      accum1(w01.z, w01.w, a0.y, a0.z, a0.w, b0.y, b0.z, b0.w, xx.y, rr, bv,
             gv, sxx, s1x);
      accum1(w23.x, w23.y, a0.z, a0.w, a1.x, b0.z, b0.w, b1.x, xx.z, rr, bv,
             gv, sxx, s1x);
      accum1(w23.z, w23.w, a0.w, a1.x, a1.y, b0.w, b1.x, b1.y, xx.w, rr, bv,
             gv, sxx, s1x);
    }
  } else {
#pragma unroll
    for (int j = 0; j < 4; ++j) {
#pragma unroll
      for (int m = 0; m < 4; ++m) {
        int k = 4 * (sub + j * gs) + m;
        float2 wp = wt[k];
        int ia = base_a + k, ib = base_b + k;
        float h0 = row[clampi(ia, T1)];
        float h1 = row[clampi(ia + 1, T1)];
        float h2 = row[clampi(ia + 2, T1)];
        float h3 = row[clampi(ib, T1)];
        float h4 = row[clampi(ib + 1, T1)];
        float h5 = row[clampi(ib + 2, T1)];
        float x = row[clampi(origin + k, T1)];
        accum1(wp.x, wp.y, h0, h1, h2, h3, h4, h5, x, rr, bv, gv, sxx, s1x);
      }
    }
  }

  // masked butterfly reduce of 29 sums within each band's lane group.
  // xor8 only band0 (16 lanes); xor4 bands 0-1; xor2/xor1 all groups.
#define RSTEP(OFF)                                              \
  do {                                                          \
    _Pragma("unroll")                                           \
    for (int i = 0; i < 21; ++i) rr[i] += __shfl_xor(rr[i], OFF, 64); \
    _Pragma("unroll")                                           \
    for (int i = 0; i < 6; ++i) bv[i] += __shfl_xor(bv[i], OFF, 64);  \
    sxx += __shfl_xor(sxx, OFF, 64);                            \
    s1x += __shfl_xor(s1x, OFF, 64);                            \
  } while (0)
  if (band == 0) RSTEP(8);
  if (band <= 1) RSTEP(4);
  RSTEP(2);
  RSTEP(1);
#undef RSTEP

  // Cholesky of R + 1e-5 I, solve for a (redundant across group lanes;
  // uniform control flow across the whole wave)
  float M[6][6], invd[6];
  {
    int c = 0;
#pragma unroll
    for (int p = 0; p < 6; ++p)
#pragma unroll
      for (int q = p; q < 6; ++q) {
        M[p][q] = rr[c];
        M[q][p] = rr[c];
        ++c;
      }
#pragma unroll
    for (int p = 0; p < 6; ++p) M[p][p] += 1e-5f;
  }
#pragma unroll
  for (int p = 0; p < 6; ++p) {
    float d = M[p][p];
#pragma unroll
    for (int j = 0; j < 6; ++j)
      if (j < p) d -= M[p][j] * M[p][j];
    d = sqrtf(d);
    M[p][p] = d;
    float inv = 1.0f / d;
    invd[p] = inv;
#pragma unroll
    for (int q = 0; q < 6; ++q)
      if (q > p) {
        float s = M[q][p];
#pragma unroll
        for (int j = 0; j < 6; ++j)
          if (j < p) s -= M[q][j] * M[p][j];
        M[q][p] = s * inv;
      }
  }
  float yv[6], av[6];
#pragma unroll
  for (int p = 0; p < 6; ++p) {
    float s = bv[p];
#pragma unroll
    for (int j = 0; j < 6; ++j)
      if (j < p) s -= M[p][j] * yv[j];
    yv[p] = s * invd[p];
  }
#pragma unroll
  for (int p = 5; p >= 0; --p) {
    float s = yv[p];
#pragma unroll
    for (int j = 0; j < 6; ++j)
      if (j > p) s -= M[j][p] * av[j];
    av[p] = s * invd[p];
  }

  // a.g: per-lane partial dot (gv unreduced), masked butterfly reduce.
  float adotg = av[0] * gv[0] + av[1] * gv[1] + av[2] * gv[2] +
                av[3] * gv[3] + av[4] * gv[4] + av[5] * gv[5];
  if (band == 0) adotg += __shfl_xor(adotg, 8, 64);
  if (band <= 1) adotg += __shfl_xor(adotg, 4, 64);
  adotg += __shfl_xor(adotg, 2, 64);
  adotg += __shfl_xor(adotg, 1, 64);

  // residual stats via exact expansion (valid for ANY a):
  //   s2r = Sxx - 2 a.b + a'Ra ;  s1r = S1x - a.g   (R without eps)
  float adotb = 0.f, quad = 0.f;
  {
    int c = 0;
#pragma unroll
    for (int p = 0; p < 6; ++p) {
      adotb += av[p] * bv[p];
#pragma unroll
      for (int q = p; q < 6; ++q) {
        float t = av[p] * av[q] * rr[c++];
        quad += (q == p) ? t : 2.f * t;
      }
    }
  }
  if (sub == 0) {
    float s2r = sxx - 2.f * adotb + quad;
    float s1r = s1x - adotg;
    const float nf = (band >= 2) ? 61.0f : (band == 1 ? 121.0f : 241.0f);
    float vx = (sxx - s1x * s1x / nf) / (nf - 1.0f);
    float vr = (s2r - s1r * s1r / nf) / (nf - 1.0f);
    float sx = sqrtf(fmaxf(vx, 0.f));
    float sr = sqrtf(fmaxf(vr, 0.f));
    lds_l[fslot][band] = __logf(sr / (sx + 1e-16f));
  }
  __syncthreads();

  // interp phase: wave w writes frames 2w and 2w+1 of this block.
  const int w = tid >> 6;
  const int lane = tid & 63;
#pragma unroll
  for (int fr = 0; fr < 2; ++fr) {
    const int fl = 2 * w + fr;
    float l0 = lds_l[fl][0];  // band0: 8000 Hz node
    float l1 = lds_l[fl][1];  // 4000
    float l2 = lds_l[fl][2];  // 2000
    float l3 = lds_l[fl][3];  // 0 & 1000 (duplicated)
    float d1 = l2 - l3, d2 = l1 - l2, d3 = l0 - l1;
    float* orow = out + (size_t)(blockIdx.x * 8 + fl) * 513;
    float vals[8];
#pragma unroll
    for (int m = 0; m < 8; ++m) {
      int k = 8 * lane + m;
      // freq = k*15.625; idx boundaries at k = 64 / 128 / 256 (exact).
      float y0, dy, c;
      int k0;
      if (k <= 64) {
        y0 = l3; dy = 0.f; k0 = 0; c = 0.015625f;     // 1/64
      } else if (k <= 128) {
        y0 = l3; dy = d1; k0 = 64; c = 0.015625f;     // 1/64
      } else if (k <= 256) {
        y0 = l2; dy = d2; k0 = 128; c = 0.0078125f;   // 1/128
      } else {
        y0 = l1; dy = d3; k0 = 256; c = 0.00390625f;  // 1/256
      }
      float wq = (float)(k - k0) * c;  // exact (matches f64-computed _WTS)
      vals[m] = __expf(y0 + wq * dy);
    }
    st4(orow + 8 * lane, make_float4(vals[0], vals[1], vals[2], vals[3]));
    st4(orow + 8 * lane + 4, make_float4(vals[4], vals[5], vals[6], vals[7]));
    if (lane == 0) orow[512] = __expf(l1 + d3);  // k=512: w=1 exactly
  }
}

extern "C" void kernel_launch(void* const* d_in, const int* in_sizes, int n_in,
                              void* d_out, int out_size, void* d_ws,
                              size_t ws_size, hipStream_t stream) {
  const float* x = (const float*)d_in[0];   // (8, 320000)
  const float* f0 = (const float*)d_in[1];  // (8, 4000)
  float* out = (float*)d_out;               // (8, 4000, 513)
  float* ws = (float*)d_ws;

  // workspace layout (floats)
  float* hx0 = ws + 0;              // 8*160000
  float* lx0 = hx0 + 1280000;       // 8*160000
  float* hx1 = lx0 + 1280000;       // 8*80000
  float* lx1 = hx1 + 640000;        // 8*80000
  float* hx2 = lx1 + 640000;        // 8*40000
  float* lx2 = hx2 + 320000;        // 8*40000
  float2* wtab = (float2*)(lx2 + 320000);  // 4*256 float2
  (void)ws_size;

  // QMF cascade (window tables initialized by stage 2's extra block)
  hipLaunchKernelGGL(qmf_kernel, dim3(5000), dim3(256), 0, stream, x, 320000,
                     hx0, lx0, (float2*)nullptr);
  hipLaunchKernelGGL(qmf_kernel, dim3(2500), dim3(256), 0, stream, lx0,
                     160000, hx1, lx1, (float2*)nullptr);
  hipLaunchKernelGGL(qmf_kernel, dim3(1251), dim3(256), 0, stream, lx1, 80000,
                     hx2, lx2, wtab);

  // mega: all 4 bands + solve + log/interp/exp, 8 frames per block
  hipLaunchKernelGGL(bands_interp_kernel, dim3(NFRAMES / 8), dim3(256), 0,
                     stream, hx0, hx1, hx2, lx2, f0, wtab, out);
}

// Round 17
// 83.092 us; speedup vs baseline: 1.1605x; 1.1605x over previous
//
#include <hip/hip_runtime.h>
#include <math.h>

#define NB 8
#define NF 4000
#define NFRAMES (NB * NF)

// ---- filter taps (first half; symmetric). Double literals -> f32 at compile
// time, matching numpy float64 -> float32 conversion exactly.
__constant__ float c_hhp[21] = {
    0.00041447996898231424, 0.0007812505141729248, -0.0010917236836275842,
    -0.001986792567596759,  0.0020903896961562292, 0.004094057027284935,
    -0.0034025808529816698, -0.007496154127205602, 0.004972263339933064,
    0.012738791249119802,   -0.006696032689574911, -0.020694051570247052,
    0.008432436565041345,   0.03307438375870053,   -0.010018936738799522,
    -0.05423136140580825,   0.011293988915051487,  0.10020081367388213,
    -0.012120546202484579,  -0.316300210390957,    0.5124068258062764};
__constant__ float c_hlp[19] = {
    -0.0006548817007748305, 7.561994958159384e-05, 0.0020408456937895227,
    -0.0007468053532203044, -0.004350223568826493, 0.0025966428382642732,
    0.007639602282756696,   -0.006490411890149785, -0.011765804538954506,
    0.013649908479276255,   0.01636866479016021,   -0.026075976030529347,
    -0.020910294856659444,  0.04826072503231665,   0.02476784661104811,
    -0.09617846758336064,   -0.027359756709866623, 0.3148805216163004,
    0.5282734359405503};

__device__ __forceinline__ int reflidx(int i, int len) {
  if (i < 0) i = -i;
  if (i >= len) i = 2 * len - 2 - i;
  return i;
}
__device__ __forceinline__ int clampi(int i, int hi) {
  return min(max(i, 0), hi);
}
// dwordx4 load/store; AMD global VMEM requires only dword alignment.
__device__ __forceinline__ float4 ld4(const float* p) {
  return *reinterpret_cast<const float4*>(p);
}
__device__ __forceinline__ void st4(float* p, float4 v) {
  *reinterpret_cast<float4*>(p) = v;
}

// ---- QMF stage body: stride-2 correlation with reflect padding.
__device__ __forceinline__ void qmf_body(const float* __restrict__ in, int len,
                                         float* __restrict__ outH,
                                         float* __restrict__ outL, int gid) {
  int half = len >> 1;
  if (gid >= NB * half) return;
  int b = gid / half;
  int nn = gid - b * half;
  const float* row = in + (size_t)b * len;
  int c = 2 * nn;
  float sh = 0.f, sl = 0.f;
  if (c >= 20 && c <= len - 22) {
    const float2* p2 = reinterpret_cast<const float2*>(row + (c - 20));
    float v[42];
#pragma unroll
    for (int j = 0; j < 21; ++j) {
      float2 t = p2[j];
      v[2 * j] = t.x;
      v[2 * j + 1] = t.y;
    }
#pragma unroll
    for (int t = 0; t < 41; ++t) sh += v[t] * c_hhp[t <= 20 ? t : 40 - t];
#pragma unroll
    for (int t = 0; t < 37; ++t) sl += v[t + 2] * c_hlp[t <= 18 ? t : 36 - t];
  } else {
#pragma unroll
    for (int t = 0; t < 41; ++t)
      sh += row[reflidx(c + t - 20, len)] * c_hhp[t <= 20 ? t : 40 - t];
#pragma unroll
    for (int t = 0; t < 37; ++t)
      sl += row[reflidx(c + t - 18, len)] * c_hlp[t <= 18 ? t : 36 - t];
  }
  outH[(size_t)b * half + nn] = sh;
  outL[(size_t)b * half + nn] = sl;
}

// ---- K1: qmf stage0; extra block initializes window tables (zero-padded to
// 256 entries per band -- the band kernels rely on those zeros).
__global__ __launch_bounds__(256) void qmf0_kernel(
    const float* __restrict__ in, float* __restrict__ outH,
    float* __restrict__ outL, float2* __restrict__ wtab) {
  int gid = blockIdx.x * 256 + threadIdx.x;
  if (gid >= NB * 160000) {
    const int segs[4] = {241, 121, 61, 61};
    int k = threadIdx.x;
    for (int i = 0; i < 4; ++i) {
      float v = 0.f;
      if (k < segs[i]) {
        double ang = 2.0 * 3.14159265358979323846 * (double)(k + 1) /
                     (double)(segs[i] + 1);
        v = (float)(0.5 - 0.5 * cos(ang));
      }
      wtab[i * 256 + k] = make_float2(v, sqrtf(v));
    }
    return;
  }
  qmf_body(in, 320000, outH, outL, gid);
}

__device__ __forceinline__ void accum1(float wk, float wsk, float h0, float h1,
                                       float h2, float h3, float h4, float h5,
                                       float x, float* __restrict__ rr,
                                       float* __restrict__ bv,
                                       float* __restrict__ gv, float& sxx,
                                       float& s1x) {
  sxx += wk * x * x;
  s1x += wsk * x;
  float wh0 = wk * h0, wh1 = wk * h1, wh2 = wk * h2, wh3 = wk * h3,
        wh4 = wk * h4, wh5 = wk * h5;
  gv[0] += wsk * h0; gv[1] += wsk * h1; gv[2] += wsk * h2;
  gv[3] += wsk * h3; gv[4] += wsk * h4; gv[5] += wsk * h5;
  bv[0] += wh0 * x;  bv[1] += wh1 * x;  bv[2] += wh2 * x;
  bv[3] += wh3 * x;  bv[4] += wh4 * x;  bv[5] += wh5 * x;
  rr[0] += wh0 * h0;  rr[1] += wh0 * h1;  rr[2] += wh0 * h2;
  rr[3] += wh0 * h3;  rr[4] += wh0 * h4;  rr[5] += wh0 * h5;
  rr[6] += wh1 * h1;  rr[7] += wh1 * h2;  rr[8] += wh1 * h3;
  rr[9] += wh1 * h4;  rr[10] += wh1 * h5; rr[11] += wh2 * h2;
  rr[12] += wh2 * h3; rr[13] += wh2 * h4; rr[14] += wh2 * h5;
  rr[15] += wh3 * h3; rr[16] += wh3 * h4; rr[17] += wh3 * h5;
  rr[18] += wh4 * h4; rr[19] += wh4 * h5; rr[20] += wh5 * h5;
}

// ---- accumulation loop: lane sub handles samples 4*(sub + j*GS) + {0..3}.
// Fast path: 7 float4 loads per 4 samples. KMAX = 4*GS*NITER (zero-padded).
template <int GS, int NITER, bool CLAMP>
__device__ __forceinline__ void acc_loop(
    const float* __restrict__ row, int T1, int base_a, int base_b, int origin,
    int sub, const float2* __restrict__ wtab, float rr[21], float bv[6],
    float gv[6], float& sxx, float& s1x) {
  if (!CLAMP) {
    const float* pa = row + base_a + 4 * sub;
    const float* pb = row + base_b + 4 * sub;
    const float* pg = row + origin + 4 * sub;
    const float* pw = reinterpret_cast<const float*>(wtab + 4 * sub);
#pragma unroll 2
    for (int j = 0; j < NITER; ++j) {
      const int off = j * 4 * GS;
      float4 a0 = ld4(pa + off);
      float4 a1 = ld4(pa + off + 4);
      float4 b0 = ld4(pb + off);
      float4 b1 = ld4(pb + off + 4);
      float4 xx = ld4(pg + off);
      float4 w01 = ld4(pw + 2 * off);
      float4 w23 = ld4(pw + 2 * off + 4);
      accum1(w01.x, w01.y, a0.x, a0.y, a0.z, b0.x, b0.y, b0.z, xx.x, rr, bv,
             gv, sxx, s1x);
      accum1(w01.z, w01.w, a0.y, a0.z, a0.w, b0.y, b0.z, b0.w, xx.y, rr, bv,
             gv, sxx, s1x);
      accum1(w23.x, w23.y, a0.z, a0.w, a1.x, b0.z, b0.w, b1.x, xx.z, rr, bv,
             gv, sxx, s1x);
      accum1(w23.z, w23.w, a0.w, a1.x, a1.y, b0.w, b1.x, b1.y, xx.w, rr, bv,
             gv, sxx, s1x);
    }
  } else {
#pragma unroll 2
    for (int j = 0; j < NITER; ++j) {
#pragma unroll
      for (int m = 0; m < 4; ++m) {
        int k = 4 * (sub + j * GS) + m;
        float2 wp = wtab[k];
        int ia = base_a + k, ib = base_b + k;
        float h0 = row[clampi(ia, T1)];
        float h1 = row[clampi(ia + 1, T1)];
        float h2 = row[clampi(ia + 2, T1)];
        float h3 = row[clampi(ib, T1)];
        float h4 = row[clampi(ib + 1, T1)];
        float h5 = row[clampi(ib + 2, T1)];
        float x = row[clampi(origin + k, T1)];
        accum1(wp.x, wp.y, h0, h1, h2, h3, h4, h5, x, rr, bv, gv, sxx, s1x);
      }
    }
  }
}

// ---- Cholesky solve + residual stats from reduced sums. Returns A.
__device__ __forceinline__ float solve_A(const float rr[21], const float bv[6],
                                         float adotg_reduced, float sxx,
                                         float s1x, float nf, float* av) {
  float M[6][6], invd[6];
  {
    int c = 0;
#pragma unroll
    for (int p = 0; p < 6; ++p)
#pragma unroll
      for (int q = p; q < 6; ++q) {
        M[p][q] = rr[c];
        M[q][p] = rr[c];
        ++c;
      }
#pragma unroll
    for (int p = 0; p < 6; ++p) M[p][p] += 1e-5f;
  }
#pragma unroll
  for (int p = 0; p < 6; ++p) {
    float d = M[p][p];
#pragma unroll
    for (int j = 0; j < 6; ++j)
      if (j < p) d -= M[p][j] * M[p][j];
    d = sqrtf(d);
    M[p][p] = d;
    float inv = 1.0f / d;
    invd[p] = inv;
#pragma unroll
    for (int q = 0; q < 6; ++q)
      if (q > p) {
        float s = M[q][p];
#pragma unroll
        for (int j = 0; j < 6; ++j)
          if (j < p) s -= M[q][j] * M[p][j];
        M[q][p] = s * inv;
      }
  }
  float yv[6];
#pragma unroll
  for (int p = 0; p < 6; ++p) {
    float s = bv[p];
#pragma unroll
    for (int j = 0; j < 6; ++j)
      if (j < p) s -= M[p][j] * yv[j];
    yv[p] = s * invd[p];
  }
#pragma unroll
  for (int p = 5; p >= 0; --p) {
    float s = yv[p];
#pragma unroll
    for (int j = 0; j < 6; ++j)
      if (j > p) s -= M[j][p] * av[j];
    av[p] = s * invd[p];
  }
  // residual stats via exact expansion (valid for ANY a):
  //   s2r = Sxx - 2 a.b + a'Ra ;  s1r = S1x - a.g   (R without eps)
  float adotb = 0.f, quad = 0.f;
  {
    int c = 0;
#pragma unroll
    for (int p = 0; p < 6; ++p) {
      adotb += av[p] * bv[p];
#pragma unroll
      for (int q = p; q < 6; ++q) {
        float t = av[p] * av[q] * rr[c++];
        quad += (q == p) ? t : 2.f * t;
      }
    }
  }
  float s2r = sxx - 2.f * adotb + quad;
  float s1r = s1x - adotg_reduced;
  float vx = (sxx - s1x * s1x / nf) / (nf - 1.0f);
  float vr = (s2r - s1r * s1r / nf) / (nf - 1.0f);
  float sx = sqrtf(fmaxf(vx, 0.f));
  float sr = sqrtf(fmaxf(vr, 0.f));
  return sr / (sx + 1e-16f);
}

// ---- per-band frame body: GS lanes per frame, 256-thread blocks.
// Accumulate + group-reduce 29 sums, fused solve (redundant on group lanes,
// measured free), store A.
template <int SEG, int LGS, int NITER>
__device__ __forceinline__ void band_body(
    const float* __restrict__ xb, int bandLen, const float* __restrict__ f0,
    float tmp_fs, const float2* __restrict__ wtab, float* __restrict__ Aout,
    int blk) {
  constexpr int GS = 1 << LGS;
  constexpr int FPB = 256 / GS;
  constexpr int KMAX = 4 * GS * NITER;
  const int tid = threadIdx.x;
  const int sub = tid & (GS - 1);
  const int frame = blk * FPB + (tid >> LGS);
  const int b = frame / NF;
  const int n = frame - b * NF;

  float f0v = f0[frame];
  if (f0v <= 32.0f) f0v = 150.0f;
  // replicate JAX f32 op sequence exactly (no FMA contraction):
  float pitch = tmp_fs / f0v;
  int t0 = (int)(__fadd_rn(pitch, 0.5f));
  int ibias = (int)(__fadd_rn(__fmul_rn(pitch, 0.5f), 0.5f));
  float tt = __fmul_rn((float)n, 0.005f);  // FRAME_PERIOD/SR as f32
  int curr = (int)(__fadd_rn(__fmul_rn(tt, tmp_fs), 1.5f));
  int origin = curr - ibias;
  const int T1 = bandLen - 1;
  const float* row = xb + (size_t)b * bandLen;
  const int base_a = origin - t0 - 1;
  const int base_b = origin + t0 - 1;

  float rr[21], bv[6], gv[6], sxx = 0.f, s1x = 0.f;
#pragma unroll
  for (int i = 0; i < 21; ++i) rr[i] = 0.f;
#pragma unroll
  for (int i = 0; i < 6; ++i) bv[i] = 0.f;
#pragma unroll
  for (int i = 0; i < 6; ++i) gv[i] = 0.f;

  const bool fast = (base_a >= 0) && (base_b + KMAX + 3 <= T1);
  if (fast)
    acc_loop<GS, NITER, false>(row, T1, base_a, base_b, origin, sub, wtab, rr,
                               bv, gv, sxx, s1x);
  else
    acc_loop<GS, NITER, true>(row, T1, base_a, base_b, origin, sub, wtab, rr,
                              bv, gv, sxx, s1x);

  // butterfly reduce rr + bv + sxx + s1x (29 values) within the group.
#pragma unroll
  for (int off = GS / 2; off >= 1; off >>= 1) {
#pragma unroll
    for (int i = 0; i < 21; ++i) rr[i] += __shfl_xor(rr[i], off, 64);
#pragma unroll
    for (int i = 0; i < 6; ++i) bv[i] += __shfl_xor(bv[i], off, 64);
    sxx += __shfl_xor(sxx, off, 64);
    s1x += __shfl_xor(s1x, off, 64);
  }

  // first solve pass needs a.g; do solve, then reduce the partial dot.
  float av[6];
  float A = solve_A(rr, bv, 0.f, sxx, s1x, (float)SEG, av);
  (void)A;  // recomputed below with correct a.g
  float adotg = av[0] * gv[0] + av[1] * gv[1] + av[2] * gv[2] +
                av[3] * gv[3] + av[4] * gv[4] + av[5] * gv[5];
#pragma unroll
  for (int off = GS / 2; off >= 1; off >>= 1)
    adotg += __shfl_xor(adotg, off, 64);

  if (sub == 0) {
    // recompute final stats with reduced a.g (cheap scalar tail)
    float adotb = 0.f, quad = 0.f;
    {
      int c = 0;
#pragma unroll
      for (int p = 0; p < 6; ++p) {
        adotb += av[p] * bv[p];
#pragma unroll
        for (int q = p; q < 6; ++q) {
          float t = av[p] * av[q] * rr[c++];
          quad += (q == p) ? t : 2.f * t;
        }
      }
    }
    const float nf = (float)SEG;
    float s2r = sxx - 2.f * adotb + quad;
    float s1r = s1x - adotg;
    float vx = (sxx - s1x * s1x / nf) / (nf - 1.0f);
    float vr = (s2r - s1r * s1r / nf) / (nf - 1.0f);
    float sx = sqrtf(fmaxf(vx, 0.f));
    float sr = sqrtf(fmaxf(vr, 0.f));
    Aout[frame] = sr / (sx + 1e-16f);
  }
}

// ---- K2: band0 (blocks [0,1000), GS=8 NITER=8) || qmf stage1 ([1000,3500)).
__global__ __launch_bounds__(256) void band0_qmf1_kernel(
    const float* __restrict__ lx0, float* __restrict__ hx1,
    float* __restrict__ lx1, const float* __restrict__ hx0,
    const float* __restrict__ f0, const float2* __restrict__ wtab,
    float* __restrict__ Aarr) {
  int blk = blockIdx.x;
  if (blk < 1000) {
    band_body<241, 3, 8>(hx0, 160000, f0, 8000.0f, wtab + 0 * 256,
                         Aarr + 0 * NFRAMES, blk);
  } else {
    qmf_body(lx0, 160000, hx1, lx1, (blk - 1000) * 256 + threadIdx.x);
  }
}

// ---- K3: band1 (blocks [0,1000), GS=8 NITER=4) || qmf stage2 ([1000,2250)).
__global__ __launch_bounds__(256) void band1_qmf2_kernel(
    const float* __restrict__ lx1, float* __restrict__ hx2,
    float* __restrict__ lx2, const float* __restrict__ hx1,
    const float* __restrict__ f0, const float2* __restrict__ wtab,
    float* __restrict__ Aarr) {
  int blk = blockIdx.x;
  if (blk < 1000) {
    band_body<121, 3, 4>(hx1, 80000, f0, 4000.0f, wtab + 1 * 256,
                         Aarr + 1 * NFRAMES, blk);
  } else {
    qmf_body(lx1, 80000, hx2, lx2, (blk - 1000) * 256 + threadIdx.x);
  }
}

// ---- K4: bands 2+3 (GS=4, 32 frames/block) + fused log/interp/exp.
// threads 0-127: band2; 128-255: band3. Band0/1 logs preloaded from Aarr.
__global__ __launch_bounds__(256) void bands23_interp_kernel(
    const float* __restrict__ hx2, const float* __restrict__ lx2,
    const float* __restrict__ f0, const float2* __restrict__ wtab,
    const float* __restrict__ Aarr, float* __restrict__ out) {
  __shared__ float lds_l[32][4];
  const int tid = threadIdx.x;
  const int blk = blockIdx.x;

  // preload band0/1 logs (frames blk*32 .. blk*32+31)
  if (tid < 64) {
    int f = tid >> 1, band = tid & 1;
    lds_l[f][band] = __logf(Aarr[band * NFRAMES + blk * 32 + f]);
  }

  // band2/3 accumulate + solve
  const int half = tid >> 7;  // 0: band2 (hx2), 1: band3 (lx2)
  const int t7 = tid & 127;
  const int sub = t7 & 3;
  const int fslot = t7 >> 2;  // 0..31
  const int frame = blk * 32 + fslot;
  const int b = frame / NF;
  const int n = frame - b * NF;
  const float* xb = half ? lx2 : hx2;
  const float2* wt = wtab + (2 + half) * 256;

  float f0v = f0[frame];
  if (f0v <= 32.0f) f0v = 150.0f;
  float pitch = 2000.0f / f0v;
  int t0 = (int)(__fadd_rn(pitch, 0.5f));
  int ibias = (int)(__fadd_rn(__fmul_rn(pitch, 0.5f), 0.5f));
  float tt = __fmul_rn((float)n, 0.005f);
  int curr = (int)(__fadd_rn(__fmul_rn(tt, 2000.0f), 1.5f));
  int origin = curr - ibias;
  const int T1 = 40000 - 1;
  const float* row = xb + (size_t)b * 40000;
  const int base_a = origin - t0 - 1;
  const int base_b = origin + t0 - 1;

  float rr[21], bv[6], gv[6], sxx = 0.f, s1x = 0.f;
#pragma unroll
  for (int i = 0; i < 21; ++i) rr[i] = 0.f;
#pragma unroll
  for (int i = 0; i < 6; ++i) bv[i] = 0.f;
#pragma unroll
  for (int i = 0; i < 6; ++i) gv[i] = 0.f;

  const bool fast = (base_a >= 0) && (base_b + 64 + 3 <= T1);
  if (fast)
    acc_loop<4, 4, false>(row, T1, base_a, base_b, origin, sub, wt, rr, bv,
                          gv, sxx, s1x);
  else
    acc_loop<4, 4, true>(row, T1, base_a, base_b, origin, sub, wt, rr, bv,
                         gv, sxx, s1x);

#pragma unroll
  for (int off = 2; off >= 1; off >>= 1) {
#pragma unroll
    for (int i = 0; i < 21; ++i) rr[i] += __shfl_xor(rr[i], off, 64);
#pragma unroll
    for (int i = 0; i < 6; ++i) bv[i] += __shfl_xor(bv[i], off, 64);
    sxx += __shfl_xor(sxx, off, 64);
    s1x += __shfl_xor(s1x, off, 64);
  }

  float av[6];
  float A0 = solve_A(rr, bv, 0.f, sxx, s1x, 61.0f, av);
  (void)A0;
  float adotg = av[0] * gv[0] + av[1] * gv[1] + av[2] * gv[2] +
                av[3] * gv[3] + av[4] * gv[4] + av[5] * gv[5];
  adotg += __shfl_xor(adotg, 2, 64);
  adotg += __shfl_xor(adotg, 1, 64);

  if (sub == 0) {
    float adotb = 0.f, quad = 0.f;
    {
      int c = 0;
#pragma unroll
      for (int p = 0; p < 6; ++p) {
        adotb += av[p] * bv[p];
#pragma unroll
        for (int q = p; q < 6; ++q) {
          float t = av[p] * av[q] * rr[c++];
          quad += (q == p) ? t : 2.f * t;
        }
      }
    }
    float s2r = sxx - 2.f * adotb + quad;
    float s1r = s1x - adotg;
    float vx = (sxx - s1x * s1x / 61.0f) / 60.0f;
    float vr = (s2r - s1r * s1r / 61.0f) / 60.0f;
    float sx = sqrtf(fmaxf(vx, 0.f));
    float sr = sqrtf(fmaxf(vr, 0.f));
    lds_l[fslot][2 + half] = __logf(sr / (sx + 1e-16f));
  }
  __syncthreads();

  // interp: 8 passes, wave w handles frame slot p*4 + w each pass.
  const int w = tid >> 6;
  const int lane = tid & 63;
#pragma unroll 2
  for (int p = 0; p < 8; ++p) {
    const int fl = p * 4 + w;
    float l0 = lds_l[fl][0];  // band0: 8000 Hz node
    float l1 = lds_l[fl][1];  // 4000
    float l2 = lds_l[fl][2];  // 2000
    float l3 = lds_l[fl][3];  // 0 & 1000 (duplicated)
    float d1 = l2 - l3, d2 = l1 - l2, d3 = l0 - l1;
    float* orow = out + (size_t)(blk * 32 + fl) * 513;
    float vals[8];
#pragma unroll
    for (int m = 0; m < 8; ++m) {
      int k = 8 * lane + m;
      // freq = k*15.625; idx boundaries at k = 64 / 128 / 256 (exact).
      float y0, dy, c;
      int k0;
      if (k <= 64) {
        y0 = l3; dy = 0.f; k0 = 0; c = 0.015625f;     // 1/64
      } else if (k <= 128) {
        y0 = l3; dy = d1; k0 = 64; c = 0.015625f;     // 1/64
      } else if (k <= 256) {
        y0 = l2; dy = d2; k0 = 128; c = 0.0078125f;   // 1/128
      } else {
        y0 = l1; dy = d3; k0 = 256; c = 0.00390625f;  // 1/256
      }
      float wq = (float)(k - k0) * c;  // exact (matches f64-computed _WTS)
      vals[m] = __expf(y0 + wq * dy);
    }
    st4(orow + 8 * lane, make_float4(vals[0], vals[1], vals[2], vals[3]));
    st4(orow + 8 * lane + 4, make_float4(vals[4], vals[5], vals[6], vals[7]));
    if (lane == 0) orow[512] = __expf(l1 + d3);  // k=512: w=1 exactly
  }
}

extern "C" void kernel_launch(void* const* d_in, const int* in_sizes, int n_in,
                              void* d_out, int out_size, void* d_ws,
                              size_t ws_size, hipStream_t stream) {
  const float* x = (const float*)d_in[0];   // (8, 320000)
  const float* f0 = (const float*)d_in[1];  // (8, 4000)
  float* out = (float*)d_out;               // (8, 4000, 513)
  float* ws = (float*)d_ws;

  // workspace layout (floats)
  float* hx0 = ws + 0;              // 8*160000
  float* lx0 = hx0 + 1280000;       // 8*160000
  float* hx1 = lx0 + 1280000;       // 8*80000
  float* lx1 = hx1 + 640000;        // 8*80000
  float* hx2 = lx1 + 640000;        // 8*40000
  float* lx2 = hx2 + 320000;        // 8*40000
  float* Aarr = lx2 + 320000;       // 2*32000 (bands 0,1)
  float2* wtab = (float2*)(Aarr + 2 * NFRAMES);  // 4*256 float2
  (void)ws_size;

  // K1: qmf stage0 (+wtab init in extra block 5000)
  hipLaunchKernelGGL(qmf0_kernel, dim3(5001), dim3(256), 0, stream, x, hx0,
                     lx0, wtab);
  // K2: band0 || qmf stage1
  hipLaunchKernelGGL(band0_qmf1_kernel, dim3(3500), dim3(256), 0, stream, lx0,
                     hx1, lx1, hx0, f0, wtab, Aarr);
  // K3: band1 || qmf stage2
  hipLaunchKernelGGL(band1_qmf2_kernel, dim3(2250), dim3(256), 0, stream, lx1,
                     hx2, lx2, hx1, f0, wtab, Aarr);
  // K4: bands 2+3 + fused log/interp/exp
  hipLaunchKernelGGL(bands23_interp_kernel, dim3(1000), dim3(256), 0, stream,
                     hx2, lx2, f0, wtab, Aarr, out);
}

// Round 18
// 78.336 us; speedup vs baseline: 1.2310x; 1.0607x over previous
//
#include <hip/hip_runtime.h>
#include <math.h>

#define NB 8
#define NF 4000
#define NFRAMES (NB * NF)

// packed upper-tri index for 6x6: row starts 0,6,11,15,18,20 (p<=q)
#define IDX(p, q)                                                      \
  ((p) == 0   ? (q)                                                    \
   : (p) == 1 ? 5 + (q)                                                \
   : (p) == 2 ? 9 + (q)                                                \
   : (p) == 3 ? 12 + (q)                                               \
   : (p) == 4 ? 14 + (q)                                               \
              : 15 + (q))

// ---- filter taps (first half; symmetric). Double literals -> f32 at compile
// time, matching numpy float64 -> float32 conversion exactly.
__constant__ float c_hhp[21] = {
    0.00041447996898231424, 0.0007812505141729248, -0.0010917236836275842,
    -0.001986792567596759,  0.0020903896961562292, 0.004094057027284935,
    -0.0034025808529816698, -0.007496154127205602, 0.004972263339933064,
    0.012738791249119802,   -0.006696032689574911, -0.020694051570247052,
    0.008432436565041345,   0.03307438375870053,   -0.010018936738799522,
    -0.05423136140580825,   0.011293988915051487,  0.10020081367388213,
    -0.012120546202484579,  -0.316300210390957,    0.5124068258062764};
__constant__ float c_hlp[19] = {
    -0.0006548817007748305, 7.561994958159384e-05, 0.0020408456937895227,
    -0.0007468053532203044, -0.004350223568826493, 0.0025966428382642732,
    0.007639602282756696,   -0.006490411890149785, -0.011765804538954506,
    0.013649908479276255,   0.01636866479016021,   -0.026075976030529347,
    -0.020910294856659444,  0.04826072503231665,   0.02476784661104811,
    -0.09617846758336064,   -0.027359756709866623, 0.3148805216163004,
    0.5282734359405503};

__device__ __forceinline__ int reflidx(int i, int len) {
  if (i < 0) i = -i;
  if (i >= len) i = 2 * len - 2 - i;
  return i;
}
__device__ __forceinline__ int clampi(int i, int hi) {
  return min(max(i, 0), hi);
}
// dwordx4 load/store; AMD global VMEM requires only dword alignment.
__device__ __forceinline__ float4 ld4(const float* p) {
  return *reinterpret_cast<const float4*>(p);
}
__device__ __forceinline__ void st4(float* p, float4 v) {
  *reinterpret_cast<float4*>(p) = v;
}

// ---- QMF stage: stride-2 correlation with reflect padding, both filters.
// If wtab != null, one extra block initializes the window tables (padded with
// zeros to 256 entries per band -- the band kernels rely on those zeros).
__global__ __launch_bounds__(256) void qmf_kernel(
    const float* __restrict__ in, int len, float* __restrict__ outH,
    float* __restrict__ outL, float2* __restrict__ wtab) {
  int half = len >> 1;
  int gid = blockIdx.x * 256 + threadIdx.x;
  if (gid >= NB * half) {
    if (wtab) {
      const int segs[4] = {241, 121, 61, 61};
      int k = threadIdx.x;
      for (int i = 0; i < 4; ++i) {
        float v = 0.f;
        if (k < segs[i]) {
          double ang = 2.0 * 3.14159265358979323846 * (double)(k + 1) /
                       (double)(segs[i] + 1);
          v = (float)(0.5 - 0.5 * cos(ang));
        }
        wtab[i * 256 + k] = make_float2(v, sqrtf(v));
      }
    }
    return;
  }
  int b = gid / half;
  int nn = gid - b * half;
  const float* row = in + (size_t)b * len;
  int c = 2 * nn;
  float sh = 0.f, sl = 0.f;
  if (c >= 20 && c <= len - 22) {
    const float2* p2 = reinterpret_cast<const float2*>(row + (c - 20));
    float v[42];
#pragma unroll
    for (int j = 0; j < 21; ++j) {
      float2 t = p2[j];
      v[2 * j] = t.x;
      v[2 * j + 1] = t.y;
    }
#pragma unroll
    for (int t = 0; t < 41; ++t) sh += v[t] * c_hhp[t <= 20 ? t : 40 - t];
#pragma unroll
    for (int t = 0; t < 37; ++t) sl += v[t + 2] * c_hlp[t <= 18 ? t : 36 - t];
  } else {
#pragma unroll
    for (int t = 0; t < 41; ++t)
      sh += row[reflidx(c + t - 20, len)] * c_hhp[t <= 20 ? t : 40 - t];
#pragma unroll
    for (int t = 0; t < 37; ++t)
      sl += row[reflidx(c + t - 18, len)] * c_hlp[t <= 18 ? t : 36 - t];
  }
  outH[(size_t)b * half + nn] = sh;
  outL[(size_t)b * half + nn] = sl;
}

__device__ __forceinline__ void accum1(float wk, float wsk, float h0, float h1,
                                       float h2, float h3, float h4, float h5,
                                       float x, float* __restrict__ rr,
                                       float* __restrict__ bv,
                                       float* __restrict__ gv, float& sxx,
                                       float& s1x) {
  sxx += wk * x * x;
  s1x += wsk * x;
  float wh0 = wk * h0, wh1 = wk * h1, wh2 = wk * h2, wh3 = wk * h3,
        wh4 = wk * h4, wh5 = wk * h5;
  gv[0] += wsk * h0; gv[1] += wsk * h1; gv[2] += wsk * h2;
  gv[3] += wsk * h3; gv[4] += wsk * h4; gv[5] += wsk * h5;
  bv[0] += wh0 * x;  bv[1] += wh1 * x;  bv[2] += wh2 * x;
  bv[3] += wh3 * x;  bv[4] += wh4 * x;  bv[5] += wh5 * x;
  rr[0] += wh0 * h0;  rr[1] += wh0 * h1;  rr[2] += wh0 * h2;
  rr[3] += wh0 * h3;  rr[4] += wh0 * h4;  rr[5] += wh0 * h5;
  rr[6] += wh1 * h1;  rr[7] += wh1 * h2;  rr[8] += wh1 * h3;
  rr[9] += wh1 * h4;  rr[10] += wh1 * h5; rr[11] += wh2 * h2;
  rr[12] += wh2 * h3; rr[13] += wh2 * h4; rr[14] += wh2 * h5;
  rr[15] += wh3 * h3; rr[16] += wh3 * h4; rr[17] += wh3 * h5;
  rr[18] += wh4 * h4; rr[19] += wh4 * h5; rr[20] += wh5 * h5;
}

// ---- accumulation loop: lane sub handles samples 4*(sub + j*GS) + {0..3}.
// Fast path: 7 float4 loads per 4 samples, unroll 1 + pointer increments to
// minimize live registers (target VGPR <= 64 for the 32-waves/CU tier).
template <int GS, int NITER, bool CLAMP>
__device__ __forceinline__ void acc_loop(
    const float* __restrict__ row, int T1, int base_a, int base_b, int origin,
    int sub, const float2* __restrict__ wtab, float rr[21], float bv[6],
    float gv[6], float& sxx, float& s1x) {
  if (!CLAMP) {
    const float* pa = row + base_a + 4 * sub;
    const float* pb = row + base_b + 4 * sub;
    const float* pg = row + origin + 4 * sub;
    const float* pw = reinterpret_cast<const float*>(wtab + 4 * sub);
#pragma unroll 1
    for (int j = 0; j < NITER; ++j) {
      float4 a0 = ld4(pa);
      float4 a1 = ld4(pa + 4);
      float4 b0 = ld4(pb);
      float4 b1 = ld4(pb + 4);
      float4 xx = ld4(pg);
      float4 w01 = ld4(pw);
      float4 w23 = ld4(pw + 4);
      accum1(w01.x, w01.y, a0.x, a0.y, a0.z, b0.x, b0.y, b0.z, xx.x, rr, bv,
             gv, sxx, s1x);
      accum1(w01.z, w01.w, a0.y, a0.z, a0.w, b0.y, b0.z, b0.w, xx.y, rr, bv,
             gv, sxx, s1x);
      accum1(w23.x, w23.y, a0.z, a0.w, a1.x, b0.z, b0.w, b1.x, xx.z, rr, bv,
             gv, sxx, s1x);
      accum1(w23.z, w23.w, a0.w, a1.x, a1.y, b0.w, b1.x, b1.y, xx.w, rr, bv,
             gv, sxx, s1x);
      pa += 4 * GS;
      pb += 4 * GS;
      pg += 4 * GS;
      pw += 8 * GS;
    }
  } else {
#pragma unroll 1
    for (int j = 0; j < NITER; ++j) {
#pragma unroll
      for (int m = 0; m < 4; ++m) {
        int k = 4 * (sub + j * GS) + m;
        float2 wp = wtab[k];
        int ia = base_a + k, ib = base_b + k;
        float h0 = row[clampi(ia, T1)];
        float h1 = row[clampi(ia + 1, T1)];
        float h2 = row[clampi(ia + 2, T1)];
        float h3 = row[clampi(ib, T1)];
        float h4 = row[clampi(ib + 1, T1)];
        float h5 = row[clampi(ib + 2, T1)];
        float x = row[clampi(origin + k, T1)];
        accum1(wp.x, wp.y, h0, h1, h2, h3, h4, h5, x, rr, bv, gv, sxx, s1x);
      }
    }
  }
}

// ---- per-band frame body: GS lanes per frame, 256-thread blocks.
// Accumulate + group-reduce 29 sums, fused IN-PLACE packed Cholesky solve
// (redundant across group lanes; fills stall cycles), store A only.
// quad form via eps-identity: a'Ra = a.b - eps*|a|^2  (since (R+eps)a = b).
template <int SEG, int LGS, int NITER>
__device__ __forceinline__ void band_body(
    const float* __restrict__ xb, int bandLen, const float* __restrict__ f0,
    float tmp_fs, const float2* __restrict__ wtab, float* __restrict__ Aout,
    int blk) {
  constexpr int GS = 1 << LGS;
  constexpr int FPB = 256 / GS;
  constexpr int KMAX = 4 * GS * NITER;
  const int tid = threadIdx.x;
  const int sub = tid & (GS - 1);
  const int frame = blk * FPB + (tid >> LGS);
  const int b = frame / NF;
  const int n = frame - b * NF;

  float f0v = f0[frame];
  if (f0v <= 32.0f) f0v = 150.0f;
  // replicate JAX f32 op sequence exactly (no FMA contraction):
  float pitch = tmp_fs / f0v;
  int t0 = (int)(__fadd_rn(pitch, 0.5f));
  int ibias = (int)(__fadd_rn(__fmul_rn(pitch, 0.5f), 0.5f));
  float tt = __fmul_rn((float)n, 0.005f);  // FRAME_PERIOD/SR as f32
  int curr = (int)(__fadd_rn(__fmul_rn(tt, tmp_fs), 1.5f));
  int origin = curr - ibias;
  const int T1 = bandLen - 1;
  const float* row = xb + (size_t)b * bandLen;
  const int base_a = origin - t0 - 1;
  const int base_b = origin + t0 - 1;

  float rr[21], bv[6], gv[6], sxx = 0.f, s1x = 0.f;
#pragma unroll
  for (int i = 0; i < 21; ++i) rr[i] = 0.f;
#pragma unroll
  for (int i = 0; i < 6; ++i) bv[i] = 0.f;
#pragma unroll
  for (int i = 0; i < 6; ++i) gv[i] = 0.f;

  const bool fast = (base_a >= 0) && (base_b + KMAX + 3 <= T1);
  if (fast)
    acc_loop<GS, NITER, false>(row, T1, base_a, base_b, origin, sub, wtab, rr,
                               bv, gv, sxx, s1x);
  else
    acc_loop<GS, NITER, true>(row, T1, base_a, base_b, origin, sub, wtab, rr,
                              bv, gv, sxx, s1x);

  // butterfly reduce rr + bv + sxx + s1x (29 values) within the group.
  // gv stays per-lane; it enters only via a.g (a is group-uniform after the
  // solve), so a partial dot + 1-scalar reduce suffices.
#pragma unroll
  for (int off = GS / 2; off >= 1; off >>= 1) {
#pragma unroll
    for (int i = 0; i < 21; ++i) rr[i] += __shfl_xor(rr[i], off, 64);
#pragma unroll
    for (int i = 0; i < 6; ++i) bv[i] += __shfl_xor(bv[i], off, 64);
    sxx += __shfl_xor(sxx, off, 64);
    s1x += __shfl_xor(s1x, off, 64);
  }

  // in-place packed Cholesky of R + 1e-5 I (rr overwritten with L factors;
  // indices all compile-time after unrolling)
  rr[0] += 1e-5f;  rr[6] += 1e-5f;  rr[11] += 1e-5f;
  rr[15] += 1e-5f; rr[18] += 1e-5f; rr[20] += 1e-5f;
  float invd[6];
#pragma unroll
  for (int p = 0; p < 6; ++p) {
    float d = rr[IDX(p, p)];
#pragma unroll
    for (int j = 0; j < 6; ++j)
      if (j < p) {
        float l = rr[IDX(j, p)];
        d -= l * l;
      }
    d = sqrtf(d);
    float inv = 1.0f / d;
    invd[p] = inv;
#pragma unroll
    for (int q = 0; q < 6; ++q)
      if (q > p) {
        float s = rr[IDX(p, q)];
#pragma unroll
        for (int j = 0; j < 6; ++j)
          if (j < p) s -= rr[IDX(j, q)] * rr[IDX(j, p)];
        rr[IDX(p, q)] = s * inv;  // = L[q][p]
      }
  }
  float yv[6], av[6];
#pragma unroll
  for (int p = 0; p < 6; ++p) {
    float s = bv[p];
#pragma unroll
    for (int j = 0; j < 6; ++j)
      if (j < p) s -= rr[IDX(j, p)] * yv[j];
    yv[p] = s * invd[p];
  }
#pragma unroll
  for (int p = 5; p >= 0; --p) {
    float s = yv[p];
#pragma unroll
    for (int j = 0; j < 6; ++j)
      if (j > p) s -= rr[IDX(p, j)] * av[j];
    av[p] = s * invd[p];
  }

  // a.g: per-lane partial dot (gv unreduced), then reduce one scalar.
  float adotg = av[0] * gv[0] + av[1] * gv[1] + av[2] * gv[2] +
                av[3] * gv[3] + av[4] * gv[4] + av[5] * gv[5];
#pragma unroll
  for (int off = GS / 2; off >= 1; off >>= 1)
    adotg += __shfl_xor(adotg, off, 64);

  if (sub == 0) {
    float adotb = av[0] * bv[0] + av[1] * bv[1] + av[2] * bv[2] +
                  av[3] * bv[3] + av[4] * bv[4] + av[5] * bv[5];
    float aa = av[0] * av[0] + av[1] * av[1] + av[2] * av[2] +
               av[3] * av[3] + av[4] * av[4] + av[5] * av[5];
    // s2r = Sxx - 2 a.b + a'Ra ; a'Ra = a.b - eps*|a|^2  =>
    float s2r = sxx - adotb - 1e-5f * aa;
    float s1r = s1x - adotg;
    const float nf = (float)SEG;
    float vx = (sxx - s1x * s1x / nf) / (nf - 1.0f);
    float vr = (s2r - s1r * s1r / nf) / (nf - 1.0f);
    float sx = sqrtf(fmaxf(vx, 0.f));
    float sr = sqrtf(fmaxf(vr, 0.f));
    Aout[frame] = sr / (sx + 1e-16f);
  }
}

// ---- all 4 bands in one launch, 256-thread blocks (round-9 geometry).
// [0,1000)    band0 GS=8 NITER=8 (KMAX=256, 32 frames/block)
// [1000,2000) band1 GS=8 NITER=4 (KMAX=128)
// [2000,2500) band2 GS=4 NITER=4 (KMAX=64, 64 frames/block)
// [2500,3000) band3 GS=4 NITER=4
__global__ __launch_bounds__(256) void bands_kernel(
    const float* __restrict__ hx0, const float* __restrict__ hx1,
    const float* __restrict__ hx2, const float* __restrict__ lx2,
    const float* __restrict__ f0, const float2* __restrict__ wtab,
    float* __restrict__ Aarr) {
  int blk = blockIdx.x;
  if (blk < 1000) {
    band_body<241, 3, 8>(hx0, 160000, f0, 8000.0f, wtab + 0 * 256,
                         Aarr + 0 * NFRAMES, blk);
  } else if (blk < 2000) {
    band_body<121, 3, 4>(hx1, 80000, f0, 4000.0f, wtab + 1 * 256,
                         Aarr + 1 * NFRAMES, blk - 1000);
  } else if (blk < 2500) {
    band_body<61, 2, 4>(hx2, 40000, f0, 2000.0f, wtab + 2 * 256,
                        Aarr + 2 * NFRAMES, blk - 2000);
  } else {
    band_body<61, 2, 4>(lx2, 40000, f0, 2000.0f, wtab + 3 * 256,
                        Aarr + 3 * NFRAMES, blk - 2500);
  }
}

// ---- fused log + interpolate + exp: one wave per frame, 4 waves/block.
// Each lane computes 8 bins (2 float4 stores); lane 0 adds the 513th bin.
__global__ __launch_bounds__(256) void interp_kernel(
    const float* __restrict__ A, float* __restrict__ out) {
  const int wave = threadIdx.x >> 6;
  const int lane = threadIdx.x & 63;
  const int f = blockIdx.x * 4 + wave;
  float l0 = __logf(A[0 * NFRAMES + f]);  // band0: 8000 Hz node
  float l1 = __logf(A[1 * NFRAMES + f]);  // 4000
  float l2 = __logf(A[2 * NFRAMES + f]);  // 2000
  float l3 = __logf(A[3 * NFRAMES + f]);  // 0 & 1000 (duplicated)
  float d1 = l2 - l3, d2 = l1 - l2, d3 = l0 - l1;
  float* orow = out + (size_t)f * 513;
  float vals[8];
#pragma unroll
  for (int m = 0; m < 8; ++m) {
    int k = 8 * lane + m;
    // freq = k*15.625; idx boundaries at k = 64 / 128 / 256 (exact).
    float y0, dy, c;
    int k0;
    if (k <= 64) {
      y0 = l3; dy = 0.f; k0 = 0; c = 0.015625f;        // 1/64
    } else if (k <= 128) {
      y0 = l3; dy = d1; k0 = 64; c = 0.015625f;        // 1/64
    } else if (k <= 256) {
      y0 = l2; dy = d2; k0 = 128; c = 0.0078125f;      // 1/128
    } else {
      y0 = l1; dy = d3; k0 = 256; c = 0.00390625f;     // 1/256
    }
    float w = (float)(k - k0) * c;  // exact (matches f64-computed _WTS)
    vals[m] = __expf(y0 + w * dy);
  }
  st4(orow + 8 * lane, make_float4(vals[0], vals[1], vals[2], vals[3]));
  st4(orow + 8 * lane + 4, make_float4(vals[4], vals[5], vals[6], vals[7]));
  if (lane == 0) orow[512] = __expf(l1 + d3);  // k=512: w=1 exactly
}

extern "C" void kernel_launch(void* const* d_in, const int* in_sizes, int n_in,
                              void* d_out, int out_size, void* d_ws,
                              size_t ws_size, hipStream_t stream) {
  const float* x = (const float*)d_in[0];   // (8, 320000)
  const float* f0 = (const float*)d_in[1];  // (8, 4000)
  float* out = (float*)d_out;               // (8, 4000, 513)
  float* ws = (float*)d_ws;

  // workspace layout (floats)
  float* hx0 = ws + 0;              // 8*160000
  float* lx0 = hx0 + 1280000;       // 8*160000
  float* hx1 = lx0 + 1280000;       // 8*80000
  float* lx1 = hx1 + 640000;        // 8*80000
  float* hx2 = lx1 + 640000;        // 8*40000
  float* lx2 = hx2 + 320000;        // 8*40000
  float* Aarr = lx2 + 320000;       // 4*32000  [band][frame]
  float2* wtab = (float2*)(Aarr + 4 * NFRAMES);  // 4*256 float2
  (void)ws_size;

  // QMF cascade (window tables initialized by stage 2's extra block)
  hipLaunchKernelGGL(qmf_kernel, dim3(5000), dim3(256), 0, stream, x, 320000,
                     hx0, lx0, (float2*)nullptr);
  hipLaunchKernelGGL(qmf_kernel, dim3(2500), dim3(256), 0, stream, lx0,
                     160000, hx1, lx1, (float2*)nullptr);
  hipLaunchKernelGGL(qmf_kernel, dim3(1251), dim3(256), 0, stream, lx1, 80000,
                     hx2, lx2, wtab);

  // all 4 bands: accumulate + reduce + fused in-place solve, store A
  hipLaunchKernelGGL(bands_kernel, dim3(3000), dim3(256), 0, stream, hx0, hx1,
                     hx2, lx2, f0, wtab, Aarr);

  // fused log + interp + exp
  hipLaunchKernelGGL(interp_kernel, dim3(NFRAMES / 4), dim3(256), 0, stream,
                     Aarr, out);
}